// Round 1
// baseline (306.283 us; speedup 1.0000x reference)
//
#include <hip/hip_runtime.h>

// Problem constants (fixed by the reference file)
#define BATCH   8
#define C_OUT   96
#define NK      11
#define C_IN    1056      // C_OUT * NK
#define GRP     4
#define HOUT    56
#define WOUT    56
#define HIN     60
#define WIN     60
#define EP      2         // extra pad

// One 64-thread block computes out_h/out_v/out_i for one (b, co, h) row of 56 outputs.
__global__ __launch_bounds__(64) void addshift_kernel(
    const float* __restrict__ x,
    const float* __restrict__ w1,
    const float* __restrict__ w2,
    const float* __restrict__ w3,
    const int*   __restrict__ pad_hv,       // (C_IN, 8)
    const int*   __restrict__ idx_identit,  // (C_OUT, 4)
    float* __restrict__ out)                // [out_h | out_v | out_i], each (B,C_OUT,HOUT,WOUT)
{
    const int h  = blockIdx.x;   // 0..55
    const int co = blockIdx.y;   // 0..95
    const int b  = blockIdx.z;   // 0..7

    __shared__ float rowbuf[NK][WIN];   // 11 x 60 floats = 2640 B

    // Stage the 11 channel rows at height h+EP (used by out_h and out_i).
    const float* xb = x + (size_t)b * C_IN * (HIN * WIN);
    const float* xrow0 = xb + (size_t)(co * NK) * (HIN * WIN) + (h + EP) * WIN;
    for (int i = threadIdx.x; i < NK * WIN; i += 64) {
        int k = i / WIN;
        int wc = i - k * WIN;
        rowbuf[k][wc] = xrow0[(size_t)k * (HIN * WIN) + wc];
    }
    __syncthreads();

    const int w = threadIdx.x;
    if (w >= WOUT) return;

    float acc_h = 0.f, acc_v = 0.f, acc_i = 0.f;

#pragma unroll
    for (int g = 0; g < GRP; ++g) {
#pragma unroll
        for (int k = 0; k < NK; ++k) {
            const int c = co * NK + k;
            // ---- horizontal shift (from LDS) ----
            const int padh = pad_hv[c * 8 + g];          // block-uniform -> scalar load
            const int iw = w + EP + padh;
            float vh = (iw >= 0 && iw < WIN) ? rowbuf[k][iw] : 0.f;
            acc_h += vh * w1[g * C_IN + c];
            // ---- vertical shift (coalesced global row read) ----
            const int padv = pad_hv[c * 8 + 4 + g];      // block-uniform
            const int ih = h + EP + padv;
            if (ih >= 0 && ih < HIN) {                   // uniform branch
                acc_v += xb[(size_t)c * (HIN * WIN) + ih * WIN + (w + EP)] * w2[g * C_IN + c];
            }
        }
        // ---- identity gather (rows already in LDS: idx in [co*NK, co*NK+NK)) ----
        const int ci = idx_identit[co * GRP + g];        // block-uniform
        acc_i += rowbuf[ci - co * NK][w + EP] * w3[g * C_OUT + co];
    }

    const size_t OSZ = (size_t)BATCH * C_OUT * HOUT * WOUT;
    const size_t o = (((size_t)b * C_OUT + co) * HOUT + h) * WOUT + w;
    out[o]            = acc_h;
    out[OSZ + o]      = acc_v;
    out[2 * OSZ + o]  = acc_i;
}

extern "C" void kernel_launch(void* const* d_in, const int* in_sizes, int n_in,
                              void* d_out, int out_size, void* d_ws, size_t ws_size,
                              hipStream_t stream) {
    const float* x   = (const float*)d_in[0];
    const float* w1  = (const float*)d_in[1];
    const float* w2  = (const float*)d_in[2];
    const float* w3  = (const float*)d_in[3];
    const int* pad_hv       = (const int*)d_in[4];
    const int* idx_identit  = (const int*)d_in[5];
    float* out = (float*)d_out;

    dim3 grid(HOUT, C_OUT, BATCH);   // h fastest -> neighboring blocks share x rows in L2
    dim3 block(64);
    addshift_kernel<<<grid, block, 0, stream>>>(x, w1, w2, w3, pad_hv, idx_identit, out);
}

// Round 2
// 239.820 us; speedup vs baseline: 1.2771x; 1.2771x over previous
//
#include <hip/hip_runtime.h>

// Problem constants (fixed by the reference file)
#define BATCH   8
#define C_OUT_N 96
#define NK      11
#define C_IN_N  1056      // C_OUT_N * NK
#define GRP     4
#define HOUT    56
#define WOUT    56
#define HIN     60
#define WIN     60
#define EP      2

// Padded LDS tile: rows ih+2+pad in [-27,78] -> 106 rows; cols iw in [-27,78]
// left col pad = 28 dwords so interior row starts stay 16B-aligned.
#define RPAD    27
#define CPADL   28
#define STRIDE  108               // dwords per padded row (432 B, 16B-aligned)
#define RTOT    106
#define TILE_DW (RTOT * STRIDE)   // 11448 dwords = 45792 B

// One block per (b, co): stages each of the 11 channels fully into a
// zero-padded LDS tile; every shift read is unconditional (pad absorbs OOB).
__global__ __launch_bounds__(256, 3) void addshift_kernel(
    const float* __restrict__ x,
    const float* __restrict__ w1,
    const float* __restrict__ w2,
    const float* __restrict__ w3,
    const int*   __restrict__ pad_hv,       // (C_IN, 8)
    const int*   __restrict__ idx_identit,  // (C_OUT, 4)
    float* __restrict__ out)                // [out_h | out_v | out_i]
{
    const int co = blockIdx.x;
    const int b  = blockIdx.y;
    const int tid = threadIdx.x;

    __shared__ __align__(16) float tile[TILE_DW];

    // One-time zero clear (pads stay zero forever; interior overwritten per k).
    {
        const float4 z4 = {0.f, 0.f, 0.f, 0.f};
        for (int j = tid; j < TILE_DW / 4; j += 256)
            ((float4*)tile)[j] = z4;
    }

    const int h0 = (tid >> 6) * 14;        // wave id * 14 rows
    const int w  = tid & 63;               // lane = output column
    const int wc = (w < WOUT) ? w : (WOUT - 1);  // clamp idle lanes' addresses

    // Block-uniform identity-gather info
    int   kI[GRP];
    float w3v[GRP];
#pragma unroll
    for (int g = 0; g < GRP; ++g) {
        kI[g]  = idx_identit[co * GRP + g] - co * NK;   // in [0, NK)
        w3v[g] = w3[g * C_OUT_N + co];
    }

    float accH[14], accV[14], accI[14];
#pragma unroll
    for (int i = 0; i < 14; ++i) { accH[i] = 0.f; accV[i] = 0.f; accI[i] = 0.f; }

    const float* chan_base = x + ((size_t)b * C_IN_N + (size_t)co * NK) * (HIN * WIN);

    // Prologue: prefetch channel k=0 into registers (900 float4 / 256 threads)
    float4 pre[4];
    {
        const float4* src4 = (const float4*)chan_base;
#pragma unroll
        for (int t = 0; t < 4; ++t) {
            int j = tid + t * 256;
            pre[t] = src4[j < 900 ? j : 899];
        }
    }

    __syncthreads();   // clear done before first interior write

    const int rowH = (h0 + EP + RPAD) * STRIDE;   // out_h / out_i base row offset
    const int colV = wc + EP + CPADL;             // fixed column index

#pragma unroll 1
    for (int k = 0; k < NK; ++k) {
        // regs -> LDS interior
#pragma unroll
        for (int t = 0; t < 4; ++t) {
            int j = tid + t * 256;
            if (j < 900) {
                int row = j / 15;
                int c4  = j - row * 15;
                *(float4*)&tile[(row + RPAD) * STRIDE + CPADL + c4 * 4] = pre[t];
            }
        }
        __syncthreads();

        // Prefetch next channel while this one computes
        if (k < NK - 1) {
            const float4* src4 = (const float4*)(chan_base + (size_t)(k + 1) * (HIN * WIN));
#pragma unroll
            for (int t = 0; t < 4; ++t) {
                int j = tid + t * 256;
                pre[t] = src4[j < 900 ? j : 899];
            }
        }

        const int c = co * NK + k;
        // Block-uniform per-channel shifts & weights
        int ph[GRP], pv[GRP];
        float a1[GRP], a2[GRP];
#pragma unroll
        for (int g = 0; g < GRP; ++g) {
            ph[g] = pad_hv[c * 8 + g];
            pv[g] = pad_hv[c * 8 + 4 + g];
            a1[g] = w1[g * C_IN_N + c];
            a2[g] = w2[g * C_IN_N + c];
        }
        float wi = 0.f;
#pragma unroll
        for (int g = 0; g < GRP; ++g)
            if (kI[g] == k) wi += w3v[g];

#pragma unroll
        for (int g = 0; g < GRP; ++g) {
            const int offH = rowH + colV + ph[g];
            const int offV = (h0 + EP + pv[g] + RPAD) * STRIDE + colV;
#pragma unroll
            for (int i = 0; i < 14; ++i) {
                accH[i] = fmaf(tile[offH + i * STRIDE], a1[g], accH[i]);
                accV[i] = fmaf(tile[offV + i * STRIDE], a2[g], accV[i]);
            }
        }
        if (wi != 0.f) {                 // block-uniform branch
            const int offI = rowH + colV;
#pragma unroll
            for (int i = 0; i < 14; ++i)
                accI[i] = fmaf(tile[offI + i * STRIDE], wi, accI[i]);
        }
        __syncthreads();   // protect tile before next k's interior writes
    }

    // Epilogue: coalesced stores
    if (w < WOUT) {
        const size_t OSZ = (size_t)BATCH * C_OUT_N * HOUT * WOUT;
        const size_t base = (((size_t)b * C_OUT_N + co) * HOUT + h0) * WOUT + w;
#pragma unroll
        for (int i = 0; i < 14; ++i) {
            out[base + (size_t)i * WOUT]            = accH[i];
            out[OSZ + base + (size_t)i * WOUT]      = accV[i];
            out[2 * OSZ + base + (size_t)i * WOUT]  = accI[i];
        }
    }
}

extern "C" void kernel_launch(void* const* d_in, const int* in_sizes, int n_in,
                              void* d_out, int out_size, void* d_ws, size_t ws_size,
                              hipStream_t stream) {
    const float* x   = (const float*)d_in[0];
    const float* w1  = (const float*)d_in[1];
    const float* w2  = (const float*)d_in[2];
    const float* w3  = (const float*)d_in[3];
    const int* pad_hv      = (const int*)d_in[4];
    const int* idx_identit = (const int*)d_in[5];
    float* out = (float*)d_out;

    dim3 grid(C_OUT_N, BATCH);   // 768 blocks = 3 per CU
    dim3 block(256);
    addshift_kernel<<<grid, block, 0, stream>>>(x, w1, w2, w3, pad_hv, idx_identit, out);
}